// Round 6
// baseline (7286.806 us; speedup 1.0000x reference)
//
#include <hip/hip_runtime.h>

#define BDIM 64
#define TDIM 1024
#define DDIM 256
#define HDIM 512

typedef unsigned short ushort_t;
typedef unsigned int uint32;
typedef unsigned long long ull;
typedef __attribute__((ext_vector_type(8))) short short8;
typedef __attribute__((ext_vector_type(4))) float f32x4;

__device__ __forceinline__ ushort_t f2bf(float f) {
  union { float f; uint32 u; } v; v.f = f;
  uint32 u = v.u;
  return (ushort_t)((u + 0x7fffu + ((u >> 16) & 1u)) >> 16);
}

__device__ __forceinline__ short8 pack8(float4 a, float4 b) {
  short8 s;
  s[0] = (short)f2bf(a.x); s[1] = (short)f2bf(a.y);
  s[2] = (short)f2bf(a.z); s[3] = (short)f2bf(a.w);
  s[4] = (short)f2bf(b.x); s[5] = (short)f2bf(b.y);
  s[6] = (short)f2bf(b.z); s[7] = (short)f2bf(b.w);
  return s;
}

__device__ __forceinline__ uint32 ld_sc1(uint32* p) {
  return __hip_atomic_load(p, __ATOMIC_RELAXED, __HIP_MEMORY_SCOPE_AGENT);
}
__device__ __forceinline__ void st_sc1(uint32* p, uint32 v) {
  __hip_atomic_store(p, v, __ATOMIC_RELAXED, __HIP_MEMORY_SCOPE_AGENT);
}
__device__ __forceinline__ void st_sc1_u64(ull* p, ull v) {
  __hip_atomic_store(p, v, __ATOMIC_RELAXED, __HIP_MEMORY_SCOPE_AGENT);
}
__device__ __forceinline__ ull ld_sc1_u64(const ull* p) {
  return __hip_atomic_load((ull*)p, __ATOMIC_RELAXED, __HIP_MEMORY_SCOPE_AGENT);
}

__device__ __forceinline__ void l1_inv() {
  asm volatile("buffer_inv sc0\n\ts_waitcnt vmcnt(0)" ::: "memory");
}

__device__ __forceinline__ void poll32_sc1(uint32* base, uint32 tgt, int lane) {
  int it = 0;
  for (;;) {
    uint32 v = ld_sc1(base + (lane & 31));
    if (__all((int)(v >= tgt))) break;
    if (++it > 30000) break;   // bounded: wrong beats hang
  }
  asm volatile("" ::: "memory");
}

// poll 128 flag words ([32 blocks][4 waves]); every lane watches 2.
__device__ __forceinline__ void poll128(uint32* base, uint32 tgt, int lane, bool fast) {
  int it = 0;
  for (;;) {
    uint32 a, c;
    if (fast) {
      l1_inv();
      a = *(volatile uint32*)(base + lane);
      c = *(volatile uint32*)(base + lane + 64);
    } else {
      a = ld_sc1(base + lane);
      c = ld_sc1(base + lane + 64);
    }
    if (__all((int)((a >= tgt) & (c >= tgt)))) break;
    if (++it > 30000) break;
  }
  asm volatile("" ::: "memory");
}

__device__ __forceinline__ void ds_stage(ushort_t* dst, int tid, const ull* v) {
#pragma unroll
  for (int q = 0; q < 8; ++q) {
    int idx = q * 256 + tid;
    int r = idx >> 7, inner = idx & 127;
    *(ull*)&dst[(r * 512 + inner * 4) ^ ((r & 7) << 3)] = v[q];
  }
}

__device__ __forceinline__ void load8(const ull* src, int tid, ull* v, bool fast) {
  if (fast) {
    l1_inv();
#pragma unroll
    for (int q = 0; q < 8; ++q) v[q] = *(const volatile ull*)(src + q * 256 + tid);
  } else {
#pragma unroll
    for (int q = 0; q < 8; ++q) v[q] = ld_sc1_u64(src + q * 256 + tid);
  }
}

__global__ void __launch_bounds__(256, 1)
lstm_fused(const float* __restrict__ x,
           const float* __restrict__ w_ih0, const float* __restrict__ w_hh0,
           const float* __restrict__ b0,
           const float* __restrict__ w_ih1, const float* __restrict__ w_hh1,
           const float* __restrict__ b1,
           float* __restrict__ out,
           uint32* cnt0F, uint32* consF, uint32* h0wF, uint32* h1wF,
           uint32* voteWs, uint32* probe,
           ushort_t* ring, ushort_t* h0loc, ushort_t* h1loc)
{
  const int b     = (int)blockIdx.x;
  const int g     = b & 7;        // group = (layer,bt); one XCD if round-robin holds
  const int layer = g >> 2;
  const int bt    = g & 3;
  const int ct    = b >> 3;       // 0..31
  const int tid   = (int)threadIdx.x;
  const int wv    = tid >> 6;
  const int lane  = tid & 63;
  const int n     = lane & 15;    // B/C column within the wave's 16
  const int rg    = lane >> 4;    // C row group
  const int gsel  = n >> 2;       // gate this lane's column belongs to
  const int cgl   = n & 3;        // h-col within the wave's 4

  __shared__ __align__(16) ushort_t IsBuf[2][16 * 512];
  __shared__ __align__(16) ushort_t Hs[16 * 512];
  __shared__ __align__(16) ushort_t htmp[4][16][4];
  __shared__ int fastLds;

  uint32* grpXcdMask = voteWs;        // [8]
  uint32* grpRep     = voteWs + 8;    // [8]
  uint32* grpBad     = voteWs + 16;   // [8]
  uint32* arrCnt     = voteWs + 24;   // [1]
  uint32* xcdAll     = voteWs + 25;   // [1]

  // ---------- one-time: marker + XCD vote ----------
  if (tid == 0) {
    uint32 xcd;
    asm volatile("s_getreg_b32 %0, hwreg(HW_REG_XCC_ID, 0, 4)" : "=s"(xcd));
    xcd &= 15u;
    *(volatile uint32*)(probe + g * 32 + ct) = 0xA5000000u | (uint32)b;
    asm volatile("s_waitcnt vmcnt(0)" ::: "memory");
    __hip_atomic_fetch_or(grpXcdMask + g, 1u << (xcd & 31u), __ATOMIC_RELAXED, __HIP_MEMORY_SCOPE_AGENT);
    __hip_atomic_fetch_or(xcdAll, 1u << (xcd & 31u), __ATOMIC_RELAXED, __HIP_MEMORY_SCOPE_AGENT);
    __hip_atomic_fetch_add(arrCnt, 1u, __ATOMIC_RELAXED, __HIP_MEMORY_SCOPE_AGENT);
    int it = 0;
    while (ld_sc1(arrCnt) < 256u) { __builtin_amdgcn_s_sleep(8); if (++it > 5000000) break; }
  }
  __syncthreads();

  // ---------- one-time: empirical L2-coherence probe ----------
  int probeOk = 1;
  if (wv == 0) {
    int seen = (lane < 32) ? 0 : 1;
    const uint32 expect = 0xA5000000u | (uint32)((lane & 31) * 8 + g);
    for (int it = 0; it < 4000 && !seen; ++it) {
      l1_inv();
      uint32 v = *(volatile uint32*)(probe + g * 32 + (lane & 31));
      if (v == expect) seen = 1;
    }
    probeOk = __all(seen);
  }
  if (tid == 0) {
    if (!probeOk) __hip_atomic_fetch_or(grpBad + g, 1u, __ATOMIC_RELAXED, __HIP_MEMORY_SCOPE_AGENT);
    __hip_atomic_fetch_add(grpRep + g, 1u, __ATOMIC_RELAXED, __HIP_MEMORY_SCOPE_AGENT);
    int it = 0;
    while (ld_sc1(grpRep + g) < 32u) { __builtin_amdgcn_s_sleep(8); if (++it > 5000000) break; }
    uint32 bad = ld_sc1(grpBad + g);
    uint32 gm  = ld_sc1(grpXcdMask + g);
    uint32 am  = ld_sc1(xcdAll);
    fastLds = (bad == 0u && __popc(gm) == 1 && __popc(am) >= 2) ? 1 : 0;
  }

  const int NI  = layer ? 16 : 8;
  const int Din = layer ? HDIM : DDIM;
  const float* wih = layer ? w_ih1 : w_ih0;
  const float* whh = layer ? w_hh1 : w_hh0;
  const float* bb  = layer ? b1 : b0;
  // column n of this wave's B tile -> weight row: gate gsel, h-col ct*16+wv*4+cgl
  const int grow = gsel * HDIM + ct * 16 + wv * 4 + cgl;

  short8 wf[32];
#pragma unroll
  for (int kf = 0; kf < 32; ++kf) wf[kf] = (short8)((short)0);
#pragma unroll
  for (int kf = 0; kf < 32; ++kf) {
    if (kf < NI + 16) {
      const float* src;
      if (kf < NI) src = wih + (size_t)grow * Din + (size_t)kf * 32 + rg * 8;
      else         src = whh + (size_t)grow * HDIM + (size_t)(kf - NI) * 32 + rg * 8;
      float4 a = *(const float4*)(src);
      float4 bq = *(const float4*)(src + 4);
      wf[kf] = pack8(a, bq);
    }
  }
  const float bias = bb[grow];

  __syncthreads();
  const bool fast = (bool)fastLds;
  const bool isg = (gsel == 3);

  const ull* ring_u = (const ull*)ring;
  ull* hloc_u = (ull*)((layer ? h1loc : h0loc)) + (size_t)bt * 4096;  // [2][16][512]
  uint32* hwF = (layer ? h1wF : h0wF) + bt * 128;                     // [32][4]
  const int xr = tid >> 4, xc = (tid & 15) * 16, xsw = (xr & 7) << 3;

  // ---------- prologue: stage input tile for t=0 into IsBuf[0] ----------
  if (layer == 0) {
    const float4* xv = (const float4*)(x + (size_t)(bt * 16 + xr) * (TDIM * DDIM) + xc);
    float4 a0 = xv[0], a1 = xv[1], a2 = xv[2], a3 = xv[3];
    *(short8*)&IsBuf[0][(xr * 512 + xc) ^ xsw]     = pack8(a0, a1);
    *(short8*)&IsBuf[0][(xr * 512 + xc + 8) ^ xsw] = pack8(a2, a3);
  } else {
    poll32_sc1(cnt0F + bt * 32, 1u, lane);
    ull rv0[8];
#pragma unroll
    for (int q = 0; q < 8; ++q)
      rv0[q] = ld_sc1_u64(ring_u + (size_t)bt * 2048 + q * 256 + tid);
    ds_stage(IsBuf[0], tid, rv0);
  }

  float c4[4] = {0.f, 0.f, 0.f, 0.f};

  for (int t = 0; t < TDIM; ++t) {
    // ---- P1: polls (all waves, redundant) ----
    if (t > 0) poll128(hwF, (uint32)t, lane, fast);
    // deferred ring flag: poll128 passing certifies ALL own-block waves' step-(t-1)
    // vmcnt drains (hwF flag is set after vmcnt(0) which covers the ring stores)
    if (layer == 0 && tid == 0 && t > 0)
      st_sc1(cnt0F + bt * 32 + ct, (uint32)t);      // y0[t-1] ready at MALL
    if (layer == 0 && t >= 8) poll32_sc1(consF + bt * 32, (uint32)(t - 7), lane);
    // ---- P2: issue loads ----
    ull hv[8];
    if (t > 0) load8(hloc_u + (size_t)((t - 1) & 1) * 2048, tid, hv, fast);
    float4 xa, xb, xc2, xd;
    ull rv[8];
    if (layer == 0) {
      if (t + 1 < TDIM) {
        const float4* xv = (const float4*)(x + (size_t)(bt * 16 + xr) * (TDIM * DDIM)
                                             + (size_t)(t + 1) * DDIM + xc);
        xa = xv[0]; xb = xv[1]; xc2 = xv[2]; xd = xv[3];
      }
    } else if (t + 1 < TDIM) {
      poll32_sc1(cnt0F + bt * 32, (uint32)(t + 2), lane);   // ring[t+1] ready
#pragma unroll
      for (int q = 0; q < 8; ++q)
        rv[q] = ld_sc1_u64(ring_u + (size_t)((t + 1) & 7) * 8192
                           + (size_t)bt * 2048 + q * 256 + tid);
    }
    // ---- P3: stage into LDS ----
    if (t > 0) ds_stage(Hs, tid, hv);
    if (layer == 0) {
      if (t + 1 < TDIM) {
        ushort_t* IsN = IsBuf[(t + 1) & 1];
        *(short8*)&IsN[(xr * 512 + xc) ^ xsw]     = pack8(xa, xb);
        *(short8*)&IsN[(xr * 512 + xc + 8) ^ xsw] = pack8(xc2, xd);
      }
    } else if (t + 1 < TDIM) {
      ds_stage(IsBuf[(t + 1) & 1], tid, rv);
    }
    __syncthreads();
    // barrier drained every thread's ring[t+1] loads -> safe to credit consumption
    if (layer == 1 && tid == 0 && t + 1 < TDIM)
      st_sc1(consF + bt * 32 + ct, (uint32)(t + 2));  // slots <= t+1 consumed

    // ---- P5: MFMA ----
    const ushort_t* IsC = IsBuf[t & 1];
    f32x4 acc0 = {0.f, 0.f, 0.f, 0.f}, acc1 = {0.f, 0.f, 0.f, 0.f};
    const int fb  = n * 512 + rg * 8;
    const int fsw = (n & 7) << 3;
#pragma unroll
    for (int kf = 0; kf < 16; ++kf) {
      if (kf < NI) {
        const short8 af = *(const short8*)&IsC[(fb + kf * 32) ^ fsw];
        if (kf & 1) acc1 = __builtin_amdgcn_mfma_f32_16x16x32_bf16(af, wf[kf], acc1, 0, 0, 0);
        else        acc0 = __builtin_amdgcn_mfma_f32_16x16x32_bf16(af, wf[kf], acc0, 0, 0, 0);
      }
    }
    if (t > 0) {
#pragma unroll
      for (int kf = 0; kf < 16; ++kf) {
        const short8 af = *(const short8*)&Hs[(fb + kf * 32) ^ fsw];
        if (kf & 1) acc1 = __builtin_amdgcn_mfma_f32_16x16x32_bf16(af, wf[NI + kf], acc1, 0, 0, 0);
        else        acc0 = __builtin_amdgcn_mfma_f32_16x16x32_bf16(af, wf[NI + kf], acc0, 0, 0, 0);
      }
    }

    // ---- P6: activation + cross-lane gate exchange + pointwise ----
    float nh4[4], nc4[4];
#pragma unroll
    for (int i = 0; i < 4; ++i) {
      float v = acc0[i] + acc1[i] + bias;
      float e = __expf(isg ? 2.f * v : -v);
      float inv = 1.f / (1.f + e);
      float act = isg ? (1.f - 2.f * inv) : inv;   // tanh for g, sigmoid else
      float fo = __shfl_xor(act, 4, 64);   // for gsel==0 lanes: f
      float oo = __shfl_xor(act, 8, 64);   // o
      float go_ = __shfl_xor(act, 12, 64); // g
      // valid on gsel==0 lanes (i=act, f=fo, o=oo, g=go_); others compute garbage
      float nc = fo * c4[i] + act * go_;
      float e2 = __expf(2.f * nc);
      float th = 1.f - 2.f / (e2 + 1.f);
      float nh = oo * th;                  // h uses UNCLIPPED c
      nc = fminf(fmaxf(nc, -50.f), 50.f);
      nh = fminf(fmaxf(nh, -50.f), 50.f);
      c4[i] = nc; nh4[i] = nh; nc4[i] = nc;
    }

    // ---- P7: publish (gsel==0 lanes own the data) ----
    const int row2 = rg * 4 + cgl;
    if (n < 4) {
#pragma unroll
      for (int i = 0; i < 4; ++i) htmp[wv][rg * 4 + i][cgl] = f2bf(nh4[i]);
      asm volatile("s_waitcnt lgkmcnt(0)" ::: "memory");
      ull hrow = *(const ull*)&htmp[wv][row2][0];   // row row2, 4 cols packed
      ull* hdst = hloc_u + (size_t)(t & 1) * 2048 + row2 * 128 + ct * 4 + wv;
      if (fast) *(volatile ull*)hdst = hrow;
      else      st_sc1_u64(hdst, hrow);
      if (layer == 0) {                             // ring copy BEFORE the vmcnt
        st_sc1_u64((ull*)ring_u + (size_t)(t & 7) * 8192
                   + (size_t)(bt * 16 + row2) * 128 + ct * 4 + wv, hrow);
      }
    }
    asm volatile("s_waitcnt vmcnt(0)" ::: "memory");   // wave's h + ring stores acked
    if (lane == 0) {
      uint32* fl = hwF + ct * 4 + wv;
      if (fast) *(volatile uint32*)fl = (uint32)(t + 1);
      else      st_sc1(fl, (uint32)(t + 1));
    }
    if (n < 4) {
      if (layer == 1) {
        const int hc = ct * 16 + wv * 4 + cgl;
#pragma unroll
        for (int i = 0; i < 4; ++i)
          out[(size_t)(bt * 16 + rg * 4 + i) * (TDIM * HDIM) + (size_t)t * HDIM + hc] = nh4[i];
      }
      if (t == TDIM - 1) {
        const size_t OH = (size_t)BDIM * TDIM * HDIM;
        const size_t OC = OH + 2 * (size_t)BDIM * HDIM;
        const int hc = ct * 16 + wv * 4 + cgl;
#pragma unroll
        for (int i = 0; i < 4; ++i) {
          out[OH + (size_t)layer * BDIM * HDIM + (size_t)(bt * 16 + rg * 4 + i) * HDIM + hc] = nh4[i];
          out[OC + (size_t)layer * BDIM * HDIM + (size_t)(bt * 16 + rg * 4 + i) * HDIM + hc] = nc4[i];
        }
      }
    }
  }

  // release y0[1023] to layer1: block barrier drains ALL waves' stores first
  if (layer == 0) {
    __syncthreads();
    if (tid == 0) st_sc1(cnt0F + bt * 32 + ct, (uint32)TDIM);
  }
}

extern "C" void kernel_launch(void* const* d_in, const int* in_sizes, int n_in,
                              void* d_out, int out_size, void* d_ws, size_t ws_size,
                              hipStream_t stream) {
  (void)in_sizes; (void)n_in; (void)out_size; (void)ws_size;
  const float* x     = (const float*)d_in[0];
  const float* w_ih0 = (const float*)d_in[1];
  const float* w_hh0 = (const float*)d_in[2];
  const float* b0    = (const float*)d_in[3];
  const float* w_ih1 = (const float*)d_in[4];
  const float* w_hh1 = (const float*)d_in[5];
  const float* b1    = (const float*)d_in[6];
  float* out = (float*)d_out;

  char* ws = (char*)d_ws;
  uint32* cnt0F  = (uint32*)(ws + 0);      // [4][32]
  uint32* consF  = (uint32*)(ws + 512);    // [4][32]
  uint32* h0wF   = (uint32*)(ws + 1024);   // [4][32][4]
  uint32* h1wF   = (uint32*)(ws + 3072);   // [4][32][4]
  uint32* voteWs = (uint32*)(ws + 5120);   // masks/counters
  uint32* probe  = (uint32*)(ws + 5248);   // [8][32]
  ushort_t* ring  = (ushort_t*)(ws + 8192);                    // [8][64][512] (512KB)
  ushort_t* h0loc = (ushort_t*)(ws + 8192 + 524288);           // [4][2][16][512] (128KB)
  ushort_t* h1loc = (ushort_t*)(ws + 8192 + 524288 + 131072);  // [4][2][16][512] (128KB)

  hipMemsetAsync(ws, 0, 8192, stream);
  lstm_fused<<<dim3(256), dim3(256), 0, stream>>>(
      x, w_ih0, w_hh0, b0, w_ih1, w_hh1, b1, out,
      cnt0F, consF, h0wF, h1wF, voteWs, probe, ring, h0loc, h1loc);
}

// Round 7
// 6283.398 us; speedup vs baseline: 1.1597x; 1.1597x over previous
//
#include <hip/hip_runtime.h>

#define BDIM 64
#define TDIM 1024
#define DDIM 256
#define HDIM 512

typedef unsigned short ushort_t;
typedef unsigned int uint32;
typedef unsigned long long ull;
typedef __attribute__((ext_vector_type(8))) short short8;
typedef __attribute__((ext_vector_type(4))) float f32x4;

__device__ __forceinline__ ushort_t f2bf(float f) {
  union { float f; uint32 u; } v; v.f = f;
  uint32 u = v.u;
  return (ushort_t)((u + 0x7fffu + ((u >> 16) & 1u)) >> 16);
}

__device__ __forceinline__ short8 pack8(float4 a, float4 b) {
  short8 s;
  s[0] = (short)f2bf(a.x); s[1] = (short)f2bf(a.y);
  s[2] = (short)f2bf(a.z); s[3] = (short)f2bf(a.w);
  s[4] = (short)f2bf(b.x); s[5] = (short)f2bf(b.y);
  s[6] = (short)f2bf(b.z); s[7] = (short)f2bf(b.w);
  return s;
}

__device__ __forceinline__ uint32 ld_sc1(uint32* p) {
  return __hip_atomic_load(p, __ATOMIC_RELAXED, __HIP_MEMORY_SCOPE_AGENT);
}
__device__ __forceinline__ void st_sc1(uint32* p, uint32 v) {
  __hip_atomic_store(p, v, __ATOMIC_RELAXED, __HIP_MEMORY_SCOPE_AGENT);
}
__device__ __forceinline__ void st_sc1_u64(ull* p, ull v) {
  __hip_atomic_store(p, v, __ATOMIC_RELAXED, __HIP_MEMORY_SCOPE_AGENT);
}
__device__ __forceinline__ ull ld_sc1_u64(const ull* p) {
  return __hip_atomic_load((ull*)p, __ATOMIC_RELAXED, __HIP_MEMORY_SCOPE_AGENT);
}

__device__ __forceinline__ void l1_inv() {
  asm volatile("buffer_inv sc0\n\ts_waitcnt vmcnt(0)" ::: "memory");
}

__device__ __forceinline__ void poll32_sc1(uint32* base, uint32 tgt, int lane) {
  int it = 0;
  for (;;) {
    uint32 v = ld_sc1(base + (lane & 31));
    if (__all((int)(v >= tgt))) break;
    if (++it > 60000) break;   // bounded: wrong beats hang
  }
  asm volatile("" ::: "memory");
}

// poll 128 flag words ([32 blocks][4 waves]); every lane watches 2.
__device__ __forceinline__ void poll128(uint32* base, uint32 tgt, int lane, bool fast) {
  int it = 0;
  for (;;) {
    uint32 a, c;
    if (fast) {
      l1_inv();
      a = *(volatile uint32*)(base + lane);
      c = *(volatile uint32*)(base + lane + 64);
    } else {
      a = ld_sc1(base + lane);
      c = ld_sc1(base + lane + 64);
    }
    if (__all((int)((a >= tgt) & (c >= tgt)))) break;
    if (++it > 60000) break;
  }
  asm volatile("" ::: "memory");
}

__device__ __forceinline__ void ds_stage(ushort_t* dst, int tid, const ull* v) {
#pragma unroll
  for (int q = 0; q < 8; ++q) {
    int idx = q * 256 + tid;
    int r = idx >> 7, inner = idx & 127;
    *(ull*)&dst[(r * 512 + inner * 4) ^ ((r & 7) << 3)] = v[q];
  }
}

// h load: no l1_inv needed — caller's poll exit did inv AFTER the producer's
// data was already in L2 (flag store is ordered after data ack), so any L1
// refill post-inv pulls fresh data.
__device__ __forceinline__ void load8(const ull* src, int tid, ull* v, bool fast) {
  if (fast) {
#pragma unroll
    for (int q = 0; q < 8; ++q) v[q] = *(const volatile ull*)(src + q * 256 + tid);
  } else {
#pragma unroll
    for (int q = 0; q < 8; ++q) v[q] = ld_sc1_u64(src + q * 256 + tid);
  }
}

__global__ void __launch_bounds__(256, 1)
lstm_fused(const float* __restrict__ x,
           const float* __restrict__ w_ih0, const float* __restrict__ w_hh0,
           const float* __restrict__ b0,
           const float* __restrict__ w_ih1, const float* __restrict__ w_hh1,
           const float* __restrict__ b1,
           float* __restrict__ out,
           uint32* cnt0F, uint32* consF, uint32* h0wF, uint32* h1wF,
           uint32* voteWs, uint32* probe,
           ushort_t* ring, ushort_t* h0loc, ushort_t* h1loc)
{
  const int b     = (int)blockIdx.x;
  const int g     = b & 7;        // group = (layer,bt); one XCD if round-robin holds
  const int layer = g >> 2;
  const int bt    = g & 3;
  const int ct    = b >> 3;       // 0..31
  const int tid   = (int)threadIdx.x;
  const int wv    = tid >> 6;
  const int lane  = tid & 63;
  const int n     = lane & 15;    // B/C column within the wave's 16
  const int rg    = lane >> 4;    // C row group
  const int gsel  = n >> 2;       // gate this lane's column belongs to
  const int cgl   = n & 3;        // h-col within the wave's 4

  __shared__ __align__(16) ushort_t IsBuf[2][16 * 512];
  __shared__ __align__(16) ushort_t Hs[16 * 512];
  __shared__ __align__(16) ushort_t htmp[4][16][4];
  __shared__ float htmpf[2][16][16];
  __shared__ int fastLds;

  uint32* grpXcdMask = voteWs;        // [8]
  uint32* grpRep     = voteWs + 8;    // [8]
  uint32* grpBad     = voteWs + 16;   // [8]
  uint32* arrCnt     = voteWs + 24;   // [1]
  uint32* xcdAll     = voteWs + 25;   // [1]

  // ---------- one-time: marker + XCD vote ----------
  if (tid == 0) {
    uint32 xcd;
    asm volatile("s_getreg_b32 %0, hwreg(HW_REG_XCC_ID, 0, 4)" : "=s"(xcd));
    xcd &= 15u;
    *(volatile uint32*)(probe + g * 32 + ct) = 0xA5000000u | (uint32)b;
    asm volatile("s_waitcnt vmcnt(0)" ::: "memory");
    __hip_atomic_fetch_or(grpXcdMask + g, 1u << (xcd & 31u), __ATOMIC_RELAXED, __HIP_MEMORY_SCOPE_AGENT);
    __hip_atomic_fetch_or(xcdAll, 1u << (xcd & 31u), __ATOMIC_RELAXED, __HIP_MEMORY_SCOPE_AGENT);
    __hip_atomic_fetch_add(arrCnt, 1u, __ATOMIC_RELAXED, __HIP_MEMORY_SCOPE_AGENT);
    int it = 0;
    while (ld_sc1(arrCnt) < 256u) { __builtin_amdgcn_s_sleep(8); if (++it > 5000000) break; }
  }
  __syncthreads();

  // ---------- one-time: empirical L2-coherence probe ----------
  int probeOk = 1;
  if (wv == 0) {
    int seen = (lane < 32) ? 0 : 1;
    const uint32 expect = 0xA5000000u | (uint32)((lane & 31) * 8 + g);
    for (int it = 0; it < 4000 && !seen; ++it) {
      l1_inv();
      uint32 v = *(volatile uint32*)(probe + g * 32 + (lane & 31));
      if (v == expect) seen = 1;
    }
    probeOk = __all(seen);
  }
  if (tid == 0) {
    if (!probeOk) __hip_atomic_fetch_or(grpBad + g, 1u, __ATOMIC_RELAXED, __HIP_MEMORY_SCOPE_AGENT);
    __hip_atomic_fetch_add(grpRep + g, 1u, __ATOMIC_RELAXED, __HIP_MEMORY_SCOPE_AGENT);
    int it = 0;
    while (ld_sc1(grpRep + g) < 32u) { __builtin_amdgcn_s_sleep(8); if (++it > 5000000) break; }
    uint32 bad = ld_sc1(grpBad + g);
    uint32 gm  = ld_sc1(grpXcdMask + g);
    uint32 am  = ld_sc1(xcdAll);
    fastLds = (bad == 0u && __popc(gm) == 1 && __popc(am) >= 2) ? 1 : 0;
  }

  const int NI  = layer ? 16 : 8;
  const int Din = layer ? HDIM : DDIM;
  const float* wih = layer ? w_ih1 : w_ih0;
  const float* whh = layer ? w_hh1 : w_hh0;
  const float* bb  = layer ? b1 : b0;
  const int grow = gsel * HDIM + ct * 16 + wv * 4 + cgl;

  short8 wf[32];
#pragma unroll
  for (int kf = 0; kf < 32; ++kf) wf[kf] = (short8)((short)0);
#pragma unroll
  for (int kf = 0; kf < 32; ++kf) {
    if (kf < NI + 16) {
      const float* src;
      if (kf < NI) src = wih + (size_t)grow * Din + (size_t)kf * 32 + rg * 8;
      else         src = whh + (size_t)grow * HDIM + (size_t)(kf - NI) * 32 + rg * 8;
      float4 a = *(const float4*)(src);
      float4 bq = *(const float4*)(src + 4);
      wf[kf] = pack8(a, bq);
    }
  }
  const float bias = bb[grow];

  __syncthreads();
  const bool fast = (bool)fastLds;
  const bool isg = (gsel == 3);

  const ull* ring_u = (const ull*)ring;
  ull* hloc_u = (ull*)((layer ? h1loc : h0loc)) + (size_t)bt * 4096;  // [2][16][512]bf16
  uint32* hwF = (layer ? h1wF : h0wF) + bt * 128;                     // [32][4]
  const int xr = tid >> 4, xc = (tid & 15) * 16, xsw = (xr & 7) << 3;

  // ---------- prologue ----------
  float4 xa, xb, xc2, xd;    // layer0: x[t+1] in regs
  ull rvA[8];                // layer1: ring[t+1] in regs
  if (layer == 0) {
    const float4* xv = (const float4*)(x + (size_t)(bt * 16 + xr) * (TDIM * DDIM) + xc);
    float4 a0 = xv[0], a1 = xv[1], a2 = xv[2], a3 = xv[3];
    *(short8*)&IsBuf[0][(xr * 512 + xc) ^ xsw]     = pack8(a0, a1);
    *(short8*)&IsBuf[0][(xr * 512 + xc + 8) ^ xsw] = pack8(a2, a3);
    const float4* xv1 = (const float4*)(x + (size_t)(bt * 16 + xr) * (TDIM * DDIM) + DDIM + xc);
    xa = xv1[0]; xb = xv1[1]; xc2 = xv1[2]; xd = xv1[3];
  } else {
    poll32_sc1(cnt0F + bt * 32, 1u, lane);       // ring[0] ready
    ull rv0[8];
#pragma unroll
    for (int q = 0; q < 8; ++q)
      rv0[q] = ld_sc1_u64(ring_u + (size_t)bt * 2048 + q * 256 + tid);
    ds_stage(IsBuf[0], tid, rv0);
    poll32_sc1(cnt0F + bt * 32, 2u, lane);       // ring[1] ready
#pragma unroll
    for (int q = 0; q < 8; ++q)
      rvA[q] = ld_sc1_u64(ring_u + (size_t)8192 + (size_t)bt * 2048 + q * 256 + tid);
  }

  float c4[4] = {0.f, 0.f, 0.f, 0.f};

  for (int t = 0; t < TDIM; ++t) {
    // ---- P1: join + deferred cross-layer flag ----
    if (t > 0) poll128(hwF, (uint32)t, lane, fast);
    if (layer == 0 && tid == 0 && t >= 2)
      st_sc1(cnt0F + bt * 32 + ct, (uint32)(t - 1));   // ring[<=t-2] certified
    if (layer == 0 && t >= 8) poll32_sc1(consF + bt * 32, (uint32)(t - 7), lane);
    // ---- P2: h chain load ----
    ull hv[8];
    if (t > 0) load8(hloc_u + (size_t)((t - 1) & 1) * 2048, tid, hv, fast);
    // ---- P3: stage ----
    if (t > 0) ds_stage(Hs, tid, hv);
    if (t + 1 < TDIM) {
      if (layer == 0) {
        ushort_t* IsN = IsBuf[(t + 1) & 1];
        *(short8*)&IsN[(xr * 512 + xc) ^ xsw]     = pack8(xa, xb);
        *(short8*)&IsN[(xr * 512 + xc + 8) ^ xsw] = pack8(xc2, xd);
      } else {
        ds_stage(IsBuf[(t + 1) & 1], tid, rvA);
      }
    }
    __syncthreads();
    // ---- post-barrier: credits + deferred out write ----
    if (layer == 1) {
      if (tid == 0) st_sc1(consF + bt * 32 + ct, (uint32)(t + 2));  // slots <= t+1 read
      if (t > 0) {
        float v = htmpf[(t - 1) & 1][tid >> 4][tid & 15];
        out[(size_t)(bt * 16 + (tid >> 4)) * (TDIM * HDIM)
            + (size_t)(t - 1) * HDIM + ct * 16 + (tid & 15)] = v;
      }
    }
    // ---- P5: MFMA (4 accumulators) ----
    const ushort_t* IsC = IsBuf[t & 1];
    f32x4 a0v = {0.f,0.f,0.f,0.f}, a1v = {0.f,0.f,0.f,0.f};
    f32x4 a2v = {0.f,0.f,0.f,0.f}, a3v = {0.f,0.f,0.f,0.f};
    const int fb  = n * 512 + rg * 8;
    const int fsw = (n & 7) << 3;
#pragma unroll
    for (int kf = 0; kf < 16; ++kf) {
      if (kf < NI) {
        const short8 af = *(const short8*)&IsC[(fb + kf * 32) ^ fsw];
        if ((kf & 3) == 0) a0v = __builtin_amdgcn_mfma_f32_16x16x32_bf16(af, wf[kf], a0v, 0, 0, 0);
        else if ((kf & 3) == 1) a1v = __builtin_amdgcn_mfma_f32_16x16x32_bf16(af, wf[kf], a1v, 0, 0, 0);
        else if ((kf & 3) == 2) a2v = __builtin_amdgcn_mfma_f32_16x16x32_bf16(af, wf[kf], a2v, 0, 0, 0);
        else                    a3v = __builtin_amdgcn_mfma_f32_16x16x32_bf16(af, wf[kf], a3v, 0, 0, 0);
      }
    }
    if (t > 0) {
#pragma unroll
      for (int kf = 0; kf < 16; ++kf) {
        const short8 af = *(const short8*)&Hs[(fb + kf * 32) ^ fsw];
        if ((kf & 3) == 0) a0v = __builtin_amdgcn_mfma_f32_16x16x32_bf16(af, wf[NI + kf], a0v, 0, 0, 0);
        else if ((kf & 3) == 1) a1v = __builtin_amdgcn_mfma_f32_16x16x32_bf16(af, wf[NI + kf], a1v, 0, 0, 0);
        else if ((kf & 3) == 2) a2v = __builtin_amdgcn_mfma_f32_16x16x32_bf16(af, wf[NI + kf], a2v, 0, 0, 0);
        else                    a3v = __builtin_amdgcn_mfma_f32_16x16x32_bf16(af, wf[NI + kf], a3v, 0, 0, 0);
      }
    }

    // ---- P6: activation + cross-lane gate exchange + pointwise ----
    float nh4[4], nc4[4];
#pragma unroll
    for (int i = 0; i < 4; ++i) {
      float v = ((a0v[i] + a1v[i]) + (a2v[i] + a3v[i])) + bias;
      float e = __expf(isg ? 2.f * v : -v);
      float inv = 1.f / (1.f + e);
      float act = isg ? (1.f - 2.f * inv) : inv;   // tanh for g, sigmoid else
      float fo = __shfl_xor(act, 4, 64);
      float oo = __shfl_xor(act, 8, 64);
      float go_ = __shfl_xor(act, 12, 64);
      float nc = fo * c4[i] + act * go_;
      float e2 = __expf(2.f * nc);
      float th = 1.f - 2.f / (e2 + 1.f);
      float nh = oo * th;                  // h uses UNCLIPPED c
      nc = fminf(fmaxf(nc, -50.f), 50.f);
      nh = fminf(fmaxf(nh, -50.f), 50.f);
      c4[i] = nc; nh4[i] = nh; nc4[i] = nc;
    }

    // ---- P7: publish ----
    const int row2 = rg * 4 + cgl;
    if (n < 4) {
      if (layer == 1) {
#pragma unroll
        for (int i = 0; i < 4; ++i) htmpf[t & 1][rg * 4 + i][wv * 4 + cgl] = nh4[i];
      }
#pragma unroll
      for (int i = 0; i < 4; ++i) htmp[wv][rg * 4 + i][cgl] = f2bf(nh4[i]);
      asm volatile("s_waitcnt lgkmcnt(0)" ::: "memory");
      ull hrow = *(const ull*)&htmp[wv][row2][0];
      ull* hdst = hloc_u + (size_t)(t & 1) * 2048 + row2 * 128 + ct * 4 + wv;
      if (fast) *(volatile ull*)hdst = hrow;
      else      st_sc1_u64(hdst, hrow);
      __builtin_amdgcn_sched_barrier(0);
      if (layer == 0) {     // ring store LAST (newest) so vmcnt(1) can exclude it
        st_sc1_u64((ull*)ring_u + (size_t)(t & 7) * 8192
                   + (size_t)(bt * 16 + row2) * 128 + ct * 4 + wv, hrow);
      }
    }
    __builtin_amdgcn_sched_barrier(0);
    if (layer == 0 && fast) asm volatile("s_waitcnt vmcnt(1)" ::: "memory");  // hloc acked, ring still in flight
    else                    asm volatile("s_waitcnt vmcnt(0)" ::: "memory");
    if (lane == 0) {
      uint32* fl = hwF + ct * 4 + wv;
      if (fast) *(volatile uint32*)fl = (uint32)(t + 1);
      else      st_sc1(fl, (uint32)(t + 1));
    }
    if (n < 4 && t == TDIM - 1) {
      const size_t OH = (size_t)BDIM * TDIM * HDIM;
      const size_t OC = OH + 2 * (size_t)BDIM * HDIM;
      const int hc = ct * 16 + wv * 4 + cgl;
#pragma unroll
      for (int i = 0; i < 4; ++i) {
        out[OH + (size_t)layer * BDIM * HDIM + (size_t)(bt * 16 + rg * 4 + i) * HDIM + hc] = nh4[i];
        out[OC + (size_t)layer * BDIM * HDIM + (size_t)(bt * 16 + rg * 4 + i) * HDIM + hc] = nc4[i];
      }
    }
    // ---- P8: prefetch issue (after flag post; drains at next step's barrier) ----
    if (layer == 0) {
      if (t + 2 < TDIM) {
        const float4* xv = (const float4*)(x + (size_t)(bt * 16 + xr) * (TDIM * DDIM)
                                             + (size_t)(t + 2) * DDIM + xc);
        xa = xv[0]; xb = xv[1]; xc2 = xv[2]; xd = xv[3];
      }
    } else {
      if (t + 2 < TDIM) {
        poll32_sc1(cnt0F + bt * 32, (uint32)(t + 3), lane);   // ring[t+2] ready
#pragma unroll
        for (int q = 0; q < 8; ++q)
          rvA[q] = ld_sc1_u64(ring_u + (size_t)((t + 2) & 7) * 8192
                              + (size_t)bt * 2048 + q * 256 + tid);
      }
    }
  }

  // ---------- epilogue ----------
  asm volatile("s_waitcnt vmcnt(0)" ::: "memory");
  __syncthreads();
  if (layer == 0) {
    if (tid == 0) st_sc1(cnt0F + bt * 32 + ct, (uint32)(TDIM + 1));  // release tail slots
  } else {
    float v = htmpf[(TDIM - 1) & 1][tid >> 4][tid & 15];
    out[(size_t)(bt * 16 + (tid >> 4)) * (TDIM * HDIM)
        + (size_t)(TDIM - 1) * HDIM + ct * 16 + (tid & 15)] = v;
  }
}

extern "C" void kernel_launch(void* const* d_in, const int* in_sizes, int n_in,
                              void* d_out, int out_size, void* d_ws, size_t ws_size,
                              hipStream_t stream) {
  (void)in_sizes; (void)n_in; (void)out_size; (void)ws_size;
  const float* x     = (const float*)d_in[0];
  const float* w_ih0 = (const float*)d_in[1];
  const float* w_hh0 = (const float*)d_in[2];
  const float* b0    = (const float*)d_in[3];
  const float* w_ih1 = (const float*)d_in[4];
  const float* w_hh1 = (const float*)d_in[5];
  const float* b1    = (const float*)d_in[6];
  float* out = (float*)d_out;

  char* ws = (char*)d_ws;
  uint32* cnt0F  = (uint32*)(ws + 0);      // [4][32]
  uint32* consF  = (uint32*)(ws + 512);    // [4][32]
  uint32* h0wF   = (uint32*)(ws + 1024);   // [4][32][4]
  uint32* h1wF   = (uint32*)(ws + 3072);   // [4][32][4]
  uint32* voteWs = (uint32*)(ws + 5120);   // masks/counters
  uint32* probe  = (uint32*)(ws + 5248);   // [8][32]
  ushort_t* ring  = (ushort_t*)(ws + 8192);                    // [8][64][512] (512KB)
  ushort_t* h0loc = (ushort_t*)(ws + 8192 + 524288);           // [4][2][16][512] (128KB)
  ushort_t* h1loc = (ushort_t*)(ws + 8192 + 524288 + 131072);  // [4][2][16][512] (128KB)

  hipMemsetAsync(ws, 0, 8192, stream);
  lstm_fused<<<dim3(256), dim3(256), 0, stream>>>(
      x, w_ih0, w_hh0, b0, w_ih1, w_hh1, b1, out,
      cnt0F, consF, h0wF, h1wF, voteWs, probe, ring, h0loc, h1loc);
}

// Round 8
// 4990.654 us; speedup vs baseline: 1.4601x; 1.2590x over previous
//
#include <hip/hip_runtime.h>

#define TDIM 1024
#define DDIM 256
#define HDIM 512
#define BDIM 64

typedef unsigned short ushort_t;
typedef unsigned int uint32;
typedef unsigned long long ull;
typedef __attribute__((ext_vector_type(8))) short short8;
typedef __attribute__((ext_vector_type(4))) float f32x4;

__device__ __forceinline__ ushort_t f2bf(float f) {
  union { float f; uint32 u; } v; v.f = f;
  uint32 u = v.u;
  return (ushort_t)((u + 0x7fffu + ((u >> 16) & 1u)) >> 16);
}

__device__ __forceinline__ short8 pack8(float4 a, float4 b) {
  short8 s;
  s[0] = (short)f2bf(a.x); s[1] = (short)f2bf(a.y);
  s[2] = (short)f2bf(a.z); s[3] = (short)f2bf(a.w);
  s[4] = (short)f2bf(b.x); s[5] = (short)f2bf(b.y);
  s[6] = (short)f2bf(b.z); s[7] = (short)f2bf(b.w);
  return s;
}

__device__ __forceinline__ uint32 ld_sc1(uint32* p) {
  return __hip_atomic_load(p, __ATOMIC_RELAXED, __HIP_MEMORY_SCOPE_AGENT);
}
__device__ __forceinline__ void st_sc1(uint32* p, uint32 v) {
  __hip_atomic_store(p, v, __ATOMIC_RELAXED, __HIP_MEMORY_SCOPE_AGENT);
}
__device__ __forceinline__ void st_sc1_u64(ull* p, ull v) {
  __hip_atomic_store(p, v, __ATOMIC_RELAXED, __HIP_MEMORY_SCOPE_AGENT);
}
__device__ __forceinline__ ull ld_sc1_u64(const ull* p) {
  return __hip_atomic_load((ull*)p, __ATOMIC_RELAXED, __HIP_MEMORY_SCOPE_AGENT);
}

// 16-word flag polls. Fast variant: L1-inv + plain load (XCD-L2 coherent).
// Both end with vmcnt(0) so subsequent plain loads can't pass a pending inv.
__device__ __forceinline__ void poll16_sc1(uint32* base, uint32 tgt, int lane, int cap) {
  int it = 0;
  for (;;) {
    uint32 v = ld_sc1(base + (lane & 15));
    if (__all((int)(v >= tgt))) break;
    if (++it > cap) break;   // bounded: wrong beats hang
  }
  asm volatile("" ::: "memory");
}
__device__ __forceinline__ void poll16_fast(const uint32* base, uint32 tgt, int lane, int cap) {
  int it = 0;
  for (;;) {
    asm volatile("buffer_inv sc0\n\ts_waitcnt vmcnt(0)" ::: "memory");
    uint32 v = *(const volatile uint32*)(base + (lane & 15));
    if (__all((int)(v >= tgt))) break;
    if (++it > cap) break;
  }
  asm volatile("s_waitcnt vmcnt(0)" ::: "memory");
}

// 512-thread staging of a 16x512 bf16 tile (2048 ull): 4 ull per thread.
__device__ __forceinline__ void ds_stage512(ushort_t* dst, int tid, const ull* v) {
#pragma unroll
  for (int q = 0; q < 4; ++q) {
    int idx = q * 512 + tid;
    int r = idx >> 7, inner = idx & 127;
    *(ull*)&dst[(r * 512 + inner * 4) ^ ((r & 7) << 3)] = v[q];
  }
}
__device__ __forceinline__ void load4_plain(const ull* src, int tid, ull* v) {
#pragma unroll
  for (int q = 0; q < 4; ++q) v[q] = *(const volatile ull*)(src + q * 512 + tid);
}
__device__ __forceinline__ void load4_sc1(const ull* src, int tid, ull* v) {
#pragma unroll
  for (int q = 0; q < 4; ++q) v[q] = ld_sc1_u64(src + q * 512 + tid);
}

__global__ void __launch_bounds__(512, 2)
lstm_fused(const float* __restrict__ x,
           const float* __restrict__ w_ih0, const float* __restrict__ w_hh0,
           const float* __restrict__ b0,
           const float* __restrict__ w_ih1, const float* __restrict__ w_hh1,
           const float* __restrict__ b1,
           float* __restrict__ out,
           uint32* cnt0F, uint32* consF, uint32* h0wF, uint32* h1wF,
           uint32* voteWs, uint32* probe,
           ushort_t* ring, ushort_t* h0loc, ushort_t* h1loc)
{
  const int b     = (int)blockIdx.x;
  const int g     = b & 7;        // (layer,bt) group -> one XCD if round-robin holds
  const int layer = g >> 2;
  const int bt    = g & 3;
  const int ct    = b >> 3;       // 0..15
  const int tid   = (int)threadIdx.x;
  const int wv    = tid >> 6;     // 0..7
  const int lane  = tid & 63;
  const int n     = lane & 15;
  const int rg    = lane >> 4;
  const int gsel  = n >> 2;       // gate of this lane's B-column
  const int cgl   = n & 3;        // h-col within the wave's 4

  __shared__ __align__(16) ushort_t IsBuf[2][16 * 512];
  __shared__ __align__(16) ushort_t Hs[16 * 512];
  __shared__ __align__(16) ushort_t htmp[8][16][4];
  __shared__ float htmpf[2][16][32];
  __shared__ int fastLds;

  uint32* grpXcdMask = voteWs;        // [8]
  uint32* grpRep     = voteWs + 8;    // [8]
  uint32* grpBad     = voteWs + 16;   // [8]
  uint32* arrCnt     = voteWs + 24;   // [1]
  uint32* xcdAll     = voteWs + 25;   // [1]

  // ---------- one-time: marker + XCD vote ----------
  if (tid == 0) {
    uint32 xcd;
    asm volatile("s_getreg_b32 %0, hwreg(HW_REG_XCC_ID, 0, 4)" : "=s"(xcd));
    xcd &= 15u;
    *(volatile uint32*)(probe + g * 16 + ct) = 0xA5000000u | (uint32)b;
    asm volatile("s_waitcnt vmcnt(0)" ::: "memory");
    __hip_atomic_fetch_or(grpXcdMask + g, 1u << (xcd & 31u), __ATOMIC_RELAXED, __HIP_MEMORY_SCOPE_AGENT);
    __hip_atomic_fetch_or(xcdAll, 1u << (xcd & 31u), __ATOMIC_RELAXED, __HIP_MEMORY_SCOPE_AGENT);
    __hip_atomic_fetch_add(arrCnt, 1u, __ATOMIC_RELAXED, __HIP_MEMORY_SCOPE_AGENT);
    int it = 0;
    while (ld_sc1(arrCnt) < 128u) { __builtin_amdgcn_s_sleep(8); if (++it > 5000000) break; }
  }
  __syncthreads();

  // ---------- one-time: empirical L2-coherence probe (fast-path mechanism) ----------
  int probeOk = 1;
  if (wv == 0) {
    int seen = (lane < 16) ? 0 : 1;
    const uint32 expect = 0xA5000000u | (uint32)((lane & 15) * 8 + g);
    for (int it = 0; it < 4000 && !seen; ++it) {
      asm volatile("buffer_inv sc0\n\ts_waitcnt vmcnt(0)" ::: "memory");
      uint32 v = *(volatile uint32*)(probe + g * 16 + (lane & 15));
      if (v == expect) seen = 1;
    }
    probeOk = __all(seen);
  }
  if (tid == 0) {
    if (!probeOk) __hip_atomic_fetch_or(grpBad + g, 1u, __ATOMIC_RELAXED, __HIP_MEMORY_SCOPE_AGENT);
    __hip_atomic_fetch_add(grpRep + g, 1u, __ATOMIC_RELAXED, __HIP_MEMORY_SCOPE_AGENT);
    int it = 0;
    while (ld_sc1(grpRep + g) < 16u) { __builtin_amdgcn_s_sleep(8); if (++it > 5000000) break; }
    uint32 bad = ld_sc1(grpBad + g);
    uint32 gm  = ld_sc1(grpXcdMask + g);
    uint32 am  = ld_sc1(xcdAll);
    fastLds = (bad == 0u && __popc(gm) == 1 && __popc(am) >= 2) ? 1 : 0;
  }

  const int NI  = layer ? 16 : 8;
  const int Din = layer ? HDIM : DDIM;
  const float* wih = layer ? w_ih1 : w_ih0;
  const float* whh = layer ? w_hh1 : w_hh0;
  const float* bb  = layer ? b1 : b0;
  const int grow = gsel * HDIM + ct * 32 + wv * 4 + cgl;

  short8 wf[32];
#pragma unroll
  for (int kf = 0; kf < 32; ++kf) wf[kf] = (short8)((short)0);
#pragma unroll
  for (int kf = 0; kf < 32; ++kf) {
    if (kf < NI + 16) {
      const float* src;
      if (kf < NI) src = wih + (size_t)grow * Din + (size_t)kf * 32 + rg * 8;
      else         src = whh + (size_t)grow * HDIM + (size_t)(kf - NI) * 32 + rg * 8;
      float4 a = *(const float4*)(src);
      float4 bq = *(const float4*)(src + 4);
      wf[kf] = pack8(a, bq);
    }
  }
  const float bias = bb[grow];

  __syncthreads();
  const bool fast = (bool)fastLds;
  const bool isg = (gsel == 3);

  const ull* ring_u = (const ull*)ring;
  ull* hloc_u = (ull*)((layer ? h1loc : h0loc)) + (size_t)bt * 4096;  // [2][16][512] bf16
  uint32* hwF   = (layer ? h1wF : h0wF) + bt * 16;                    // [16]
  uint32* c0F   = cnt0F + bt * 16;                                    // [16]
  uint32* cnsF  = consF + bt * 16;                                    // [16]
  const int xr = tid >> 5, xc = (tid & 31) * 8, xsw = (xr & 7) << 3;  // x staging map

  // ---------- prologue ----------
  float4 xpa, xpb;           // layer0: x[t+1] regs (8 floats)
  ull rvA[4];                // layer1: ring[t+1] regs
  if (layer == 0) {
    const float4* xv = (const float4*)(x + (size_t)(bt * 16 + xr) * (TDIM * DDIM) + xc);
    float4 a0 = xv[0], a1 = xv[1];
    *(short8*)&IsBuf[0][(xr * 512 + xc) ^ xsw] = pack8(a0, a1);
    const float4* xv1 = (const float4*)(x + (size_t)(bt * 16 + xr) * (TDIM * DDIM) + DDIM + xc);
    xpa = xv1[0]; xpb = xv1[1];
  } else {
    poll16_sc1(c0F, 1u, lane, 4000000);       // ring[0] certified
    ull rv0[4];
    load4_sc1(ring_u + (size_t)bt * 2048, tid, rv0);
    ds_stage512(IsBuf[0], tid, rv0);
    poll16_sc1(c0F, 2u, lane, 4000000);       // ring[1] certified
    load4_sc1(ring_u + 8192 + (size_t)bt * 2048, tid, rvA);
  }

  float c4[4] = {0.f, 0.f, 0.f, 0.f};

  for (int t = 0; t < TDIM; ++t) {
    // ---- P1: chain join ----
    if (t > 0) {
      if (fast) poll16_fast(hwF, (uint32)t, lane, 100000);
      else      poll16_sc1(hwF, (uint32)t, lane, 100000);
    }
    if (layer == 0 && t >= 8) poll16_sc1(cnsF, (uint32)(t - 6), lane, 100000);
    // ---- P2: h[t-1] load (16KB across 512 threads) ----
    ull hv[4];
    if (t > 0) {
      if (fast) load4_plain(hloc_u + (size_t)((t - 1) & 1) * 2048, tid, hv);
      else      load4_sc1(hloc_u + (size_t)((t - 1) & 1) * 2048, tid, hv);
    }
    // ---- P3: stage ----
    if (t > 0) ds_stage512(Hs, tid, hv);
    if (t + 1 < TDIM) {
      if (layer == 0) {
        *(short8*)&IsBuf[(t + 1) & 1][(xr * 512 + xc) ^ xsw] = pack8(xpa, xpb);
      } else {
        ds_stage512(IsBuf[(t + 1) & 1], tid, rvA);
      }
    }
    __syncthreads();   // B1
    // ---- post-B1: ring credit + deferred coalesced out[t-1] ----
    if (layer == 1) {
      if (tid == 0) st_sc1(cnsF + ct, (uint32)(t + 2));   // slots <= t+1 consumed
      if (t > 0) {
        float v = htmpf[(t - 1) & 1][tid >> 5][tid & 31];
        out[(size_t)(bt * 16 + (tid >> 5)) * (TDIM * HDIM)
            + (size_t)(t - 1) * HDIM + ct * 32 + (tid & 31)] = v;
      }
    }
    // ---- P5: MFMA (4 accumulators) ----
    const ushort_t* IsC = IsBuf[t & 1];
    f32x4 a0v = {0.f,0.f,0.f,0.f}, a1v = {0.f,0.f,0.f,0.f};
    f32x4 a2v = {0.f,0.f,0.f,0.f}, a3v = {0.f,0.f,0.f,0.f};
    const int fb  = n * 512 + rg * 8;
    const int fsw = (n & 7) << 3;
#pragma unroll
    for (int kf = 0; kf < 16; ++kf) {
      if (kf < NI) {
        const short8 af = *(const short8*)&IsC[(fb + kf * 32) ^ fsw];
        if ((kf & 3) == 0) a0v = __builtin_amdgcn_mfma_f32_16x16x32_bf16(af, wf[kf], a0v, 0, 0, 0);
        else if ((kf & 3) == 1) a1v = __builtin_amdgcn_mfma_f32_16x16x32_bf16(af, wf[kf], a1v, 0, 0, 0);
        else if ((kf & 3) == 2) a2v = __builtin_amdgcn_mfma_f32_16x16x32_bf16(af, wf[kf], a2v, 0, 0, 0);
        else                    a3v = __builtin_amdgcn_mfma_f32_16x16x32_bf16(af, wf[kf], a3v, 0, 0, 0);
      }
    }
    if (t > 0) {
#pragma unroll
      for (int kf = 0; kf < 16; ++kf) {
        const short8 af = *(const short8*)&Hs[(fb + kf * 32) ^ fsw];
        if ((kf & 3) == 0) a0v = __builtin_amdgcn_mfma_f32_16x16x32_bf16(af, wf[NI + kf], a0v, 0, 0, 0);
        else if ((kf & 3) == 1) a1v = __builtin_amdgcn_mfma_f32_16x16x32_bf16(af, wf[NI + kf], a1v, 0, 0, 0);
        else if ((kf & 3) == 2) a2v = __builtin_amdgcn_mfma_f32_16x16x32_bf16(af, wf[NI + kf], a2v, 0, 0, 0);
        else                    a3v = __builtin_amdgcn_mfma_f32_16x16x32_bf16(af, wf[NI + kf], a3v, 0, 0, 0);
      }
    }
    // ---- P6: activation + shfl gate exchange + pointwise ----
    float nh4[4], nc4[4];
#pragma unroll
    for (int i = 0; i < 4; ++i) {
      float v = ((a0v[i] + a1v[i]) + (a2v[i] + a3v[i])) + bias;
      float e = __expf(isg ? 2.f * v : -v);
      float inv = 1.f / (1.f + e);
      float act = isg ? (1.f - 2.f * inv) : inv;   // tanh for g, sigmoid else
      float fo  = __shfl_xor(act, 4, 64);
      float oo  = __shfl_xor(act, 8, 64);
      float go_ = __shfl_xor(act, 12, 64);
      float nc = fo * c4[i] + act * go_;           // valid on gsel==0 lanes
      float e2 = __expf(2.f * nc);
      float th = 1.f - 2.f / (e2 + 1.f);
      float nh = oo * th;                          // h uses UNCLIPPED c
      nc = fminf(fmaxf(nc, -50.f), 50.f);
      nh = fminf(fmaxf(nh, -50.f), 50.f);
      c4[i] = nc; nh4[i] = nh; nc4[i] = nc;
    }
    // ---- P7: publish ----
    const int row2 = rg * 4 + cgl;
    if (n < 4) {
#pragma unroll
      for (int i = 0; i < 4; ++i) htmp[wv][rg * 4 + i][cgl] = f2bf(nh4[i]);
      if (layer == 1) {
#pragma unroll
        for (int i = 0; i < 4; ++i) htmpf[t & 1][rg * 4 + i][wv * 4 + cgl] = nh4[i];
      }
      asm volatile("s_waitcnt lgkmcnt(0)" ::: "memory");
      ull hrow = *(const ull*)&htmp[wv][row2][0];    // 4x4 lane transpose via LDS
      ull* hdst = hloc_u + (size_t)(t & 1) * 2048 + row2 * 128 + ct * 8 + wv;
      if (fast) *(volatile ull*)hdst = hrow;
      else      st_sc1_u64(hdst, hrow);
      __builtin_amdgcn_sched_barrier(0);
      if (layer == 0) {   // ring store LAST so vmcnt(1) can exclude its MALL ack
        st_sc1_u64((ull*)ring_u + (size_t)(t & 7) * 8192
                   + (size_t)(bt * 16 + row2) * 128 + ct * 8 + wv, hrow);
      }
      if (t == TDIM - 1) {
        const size_t OH = (size_t)BDIM * TDIM * HDIM;
        const size_t OC = OH + 2 * (size_t)BDIM * HDIM;
        const int hc = ct * 32 + wv * 4 + cgl;
#pragma unroll
        for (int i = 0; i < 4; ++i) {
          out[OH + (size_t)layer * BDIM * HDIM + (size_t)(bt * 16 + rg * 4 + i) * HDIM + hc] = nh4[i];
          out[OC + (size_t)layer * BDIM * HDIM + (size_t)(bt * 16 + rg * 4 + i) * HDIM + hc] = nc4[i];
        }
      }
    }
    __builtin_amdgcn_sched_barrier(0);
    if (layer == 0 && t < TDIM - 1) asm volatile("s_waitcnt vmcnt(1)" ::: "memory");
    else                            asm volatile("s_waitcnt vmcnt(0)" ::: "memory");
    __syncthreads();   // B2: all waves' publishes certified
    if (tid == 0) {
      if (fast) *(volatile uint32*)(hwF + ct) = (uint32)(t + 1);
      else      st_sc1(hwF + ct, (uint32)(t + 1));
      // lag-1 ring flag: this step's vmcnt(1) left only ring[t] in flight,
      // so ring[t-1] (issued last step) is certainly acked.
      if (layer == 0 && t >= 1) st_sc1(c0F + ct, (uint32)t);
    }
    // ---- P8: shadow prefetch (drains under next step's poll) ----
    if (layer == 0) {
      if (t + 2 < TDIM) {
        const float4* xv = (const float4*)(x + (size_t)(bt * 16 + xr) * (TDIM * DDIM)
                                             + (size_t)(t + 2) * DDIM + xc);
        xpa = xv[0]; xpb = xv[1];
      }
    } else if (t + 2 < TDIM) {
      poll16_sc1(c0F, (uint32)(t + 3), lane, 100000);   // ring[t+2] certified
      load4_sc1(ring_u + (size_t)((t + 2) & 7) * 8192 + (size_t)bt * 2048, tid, rvA);
    }
  }

  // ---------- epilogue ----------
  asm volatile("s_waitcnt vmcnt(0)" ::: "memory");
  __syncthreads();
  if (layer == 0) {
    if (tid == 0) st_sc1(c0F + ct, (uint32)(TDIM + 8));   // release all tail polls
  } else {
    float v = htmpf[(TDIM - 1) & 1][tid >> 5][tid & 31];
    out[(size_t)(bt * 16 + (tid >> 5)) * (TDIM * HDIM)
        + (size_t)(TDIM - 1) * HDIM + ct * 32 + (tid & 31)] = v;
  }
}

extern "C" void kernel_launch(void* const* d_in, const int* in_sizes, int n_in,
                              void* d_out, int out_size, void* d_ws, size_t ws_size,
                              hipStream_t stream) {
  (void)in_sizes; (void)n_in; (void)out_size; (void)ws_size;
  const float* x     = (const float*)d_in[0];
  const float* w_ih0 = (const float*)d_in[1];
  const float* w_hh0 = (const float*)d_in[2];
  const float* b0    = (const float*)d_in[3];
  const float* w_ih1 = (const float*)d_in[4];
  const float* w_hh1 = (const float*)d_in[5];
  const float* b1    = (const float*)d_in[6];
  float* out = (float*)d_out;

  char* ws = (char*)d_ws;
  uint32* cnt0F  = (uint32*)(ws + 0);      // [4][16]
  uint32* consF  = (uint32*)(ws + 256);    // [4][16]
  uint32* h0wF   = (uint32*)(ws + 512);    // [4][16]
  uint32* h1wF   = (uint32*)(ws + 768);    // [4][16]
  uint32* voteWs = (uint32*)(ws + 1024);   // masks/counters
  uint32* probe  = (uint32*)(ws + 1280);   // [8][16]
  ushort_t* ring  = (ushort_t*)(ws + 8192);                    // [8][64][512] bf16 (512KB)
  ushort_t* h0loc = (ushort_t*)(ws + 8192 + 524288);           // [4][2][16][512] (128KB)
  ushort_t* h1loc = (ushort_t*)(ws + 8192 + 524288 + 131072);  // [4][2][16][512] (128KB)

  hipMemsetAsync(ws, 0, 8192, stream);
  lstm_fused<<<dim3(128), dim3(512), 0, stream>>>(
      x, w_ih0, w_hh0, b0, w_ih1, w_hh1, b1, out,
      cnt0F, consF, h0wF, h1wF, voteWs, probe, ring, h0loc, h1loc);
}